// Round 1
// baseline (402.058 us; speedup 1.0000x reference)
//
#include <hip/hip_runtime.h>
#include <hip/hip_fp16.h>

typedef unsigned short u16;
typedef _Float16 half8 __attribute__((ext_vector_type(8)));
typedef float floatx4 __attribute__((ext_vector_type(4)));

#define C_DIM 256
#define P_DIM 2048
#define L_DIM 1024
#define N_DIM 16
#define KEEP 102
#define KPAD 104
#define HALF_PIX 8192   // pixels per half-pass
#define SCALE 256.0f    // 2^8 input pre-scale; both operands scaled -> acc at 2^16.
                        // Downstream is scale-invariant (topk order + w/Sum(w)).

__device__ __forceinline__ void st8(u16* dst, const u16* s) {
  uint4 u;
  u.x = (unsigned)s[0] | ((unsigned)s[1] << 16);
  u.y = (unsigned)s[2] | ((unsigned)s[3] << 16);
  u.z = (unsigned)s[4] | ((unsigned)s[5] << 16);
  u.w = (unsigned)s[6] | ((unsigned)s[7] << 16);
  *(uint4*)dst = u;
}

// ---------------- kernel 1a: pinv[p] = 1/||pool_p|| ----------------
__global__ __launch_bounds__(256) void k_pinv(const float* __restrict__ pool,
                                              float* __restrict__ pinv) {
  int p = blockIdx.x * 256 + threadIdx.x;
  const float4* row = (const float4*)(pool + (size_t)p * C_DIM);
  float s = 0.f;
#pragma unroll
  for (int i = 0; i < C_DIM / 4; ++i) {
    float4 v = row[i];
    s += v.x * v.x + v.y * v.y + v.z * v.z + v.w * v.w;
  }
  pinv[p] = 1.0f / sqrtf(s);
}

// ------- kernel 1b: pack pool*pinv*2^8 into MFMA-A frag order, fp16 hi/lo split,
//         and a raw fp16 copy of pool for the recon gather -------------------
// frag element (pm, ks, lane, j): p = pm*16 + (lane&15), c = ks*32 + (lane>>4)*8 + j
__global__ __launch_bounds__(256) void k_packpool(const float* __restrict__ pool,
                                                  const float* __restrict__ pinv,
                                                  u16* __restrict__ ah,
                                                  u16* __restrict__ al,
                                                  u16* __restrict__ ph) {
  int tid = blockIdx.x * 256 + threadIdx.x;     // 65536 = 128*8*64
  int lane = tid & 63;
  int ks = (tid >> 6) & 7;
  int pm = tid >> 9;
  int p = pm * 16 + (lane & 15);
  int c0 = ks * 32 + ((lane >> 4) << 3);
  float sc = pinv[p] * SCALE;
  const float* src = pool + (size_t)p * C_DIM + c0;
  u16 h8[8], l8[8], p8[8];
#pragma unroll
  for (int j = 0; j < 8; ++j) {
    float raw = src[j];
    p8[j] = __half_as_ushort(__float2half(raw));
    float v = raw * sc;
    __half h = __float2half(v);          // RNE
    float r = v - __half2float(h);       // exact (Sterbenz range)
    h8[j] = __half_as_ushort(h);
    l8[j] = __half_as_ushort(__float2half(r));
  }
  size_t o = (size_t)tid * 8;
  st8(ah + o, h8); st8(al + o, l8);
  st8(ph + (size_t)p * C_DIM + c0, p8);
}

// ------- kernel 1c: pack x*2^8 into MFMA-B fragment order, fp16 hi/lo split ----
// frag element (pn, ks, lane, j): pix = pn*16 + (lane&15), c = ks*32 + (lane>>4)*8 + j
__global__ __launch_bounds__(256) void k_packx(const float* __restrict__ x,
                                               u16* __restrict__ xh,
                                               u16* __restrict__ xl) {
  int tid = blockIdx.x * 256 + threadIdx.x;     // 524288 = 1024*8*64
  int lane = tid & 63;
  int ks = (tid >> 6) & 7;
  int pn = tid >> 9;
  int pix = pn * 16 + (lane & 15);
  int n = pix >> 10, l = pix & 1023;
  int c0 = ks * 32 + ((lane >> 4) << 3);
  const float* src = x + ((size_t)(n * C_DIM + c0)) * L_DIM + l;
  u16 h8[8], l8[8];
#pragma unroll
  for (int j = 0; j < 8; ++j) {
    float v = src[(size_t)j * L_DIM] * SCALE;
    __half h = __float2half(v);
    float r = v - __half2float(h);
    h8[j] = __half_as_ushort(h);
    l8[j] = __half_as_ushort(__float2half(r));
  }
  size_t o = (size_t)tid * 8;
  st8(xh + o, h8); st8(xl + o, l8);
}

// ---------------- kernel A: sbuf[pixLocal][p] via fp16x2 MFMA (3 products) ---
// One half (8192 pixels). grid 1024 = pT(16) x pixT(64); 256 thr / 4 waves.
__global__ __launch_bounds__(256, 3) void k_mfma(const u16* __restrict__ ah_,
                                                 const u16* __restrict__ al_,
                                                 const u16* __restrict__ xh_,
                                                 const u16* __restrict__ xl_,
                                                 float* __restrict__ sbuf,
                                                 int half) {
  const int t = threadIdx.x, lane = t & 63, w = t >> 6;
  const int pT = blockIdx.x & 15, pixT = blockIdx.x >> 4;   // pixT 0..63
  const int pmBase = pT * 8 + w * 2;
  const int pnBase = half * 512 + pixT * 8;
  const half8* A8h = (const half8*)ah_;
  const half8* A8l = (const half8*)al_;
  const half8* B8h = (const half8*)xh_;
  const half8* B8l = (const half8*)xl_;

  floatx4 acc[2][8];
#pragma unroll
  for (int mt = 0; mt < 2; ++mt)
#pragma unroll
    for (int nt = 0; nt < 8; ++nt) acc[mt][nt] = (floatx4){0.f, 0.f, 0.f, 0.f};

#pragma unroll 1
  for (int ks = 0; ks < 8; ++ks) {
    const size_t ao = (size_t)ks * 64 + lane;
    half8 aH[2], aL[2];
#pragma unroll
    for (int mt = 0; mt < 2; ++mt) {
      size_t idx = (size_t)(pmBase + mt) * 512 + ao;
      aH[mt] = A8h[idx]; aL[mt] = A8l[idx];
    }
#pragma unroll
    for (int nt = 0; nt < 8; ++nt) {
      size_t bidx = (size_t)(pnBase + nt) * 512 + ao;
      half8 bh = B8h[bidx], bl = B8l[bidx];
#pragma unroll
      for (int mt = 0; mt < 2; ++mt) {
        floatx4 c = acc[mt][nt];
        c = __builtin_amdgcn_mfma_f32_16x16x32_f16(aH[mt], bh, c, 0, 0, 0);
        c = __builtin_amdgcn_mfma_f32_16x16x32_f16(aH[mt], bl, c, 0, 0, 0);
        c = __builtin_amdgcn_mfma_f32_16x16x32_f16(aL[mt], bh, c, 0, 0, 0);
        acc[mt][nt] = c;
      }
    }
  }

  const int qr = lane >> 4, cl = lane & 15;
  const int pix0 = pixT * 128;
  const int pbase = pT * 128 + w * 32;
#pragma unroll
  for (int mt = 0; mt < 2; ++mt)
#pragma unroll
    for (int nt = 0; nt < 8; ++nt) {
      float* dst = sbuf + (size_t)(pix0 + nt * 16 + cl) * P_DIM + pbase + mt * 16 + qr * 4;
      *(float4*)dst = make_float4(acc[mt][nt][0], acc[mt][nt][1],
                                  acc[mt][nt][2], acc[mt][nt][3]);
    }
}

// ---------------- kernel B: per-pixel top-102 select + renorm + recon ----
// One half. 512 threads = 8 waves; wave wv owns one pixel. 1024 blocks.
// value (q, rr) at lane: p = q*256 + lane*4 + rr
__global__ __launch_bounds__(512) void k_select(const float* __restrict__ sbuf,
                                                const u16* __restrict__ pool_h,
                                                float* __restrict__ out,
                                                int half) {
  __shared__ __align__(16) float tbuf[8][260];
  __shared__ int2 kpw[8][KPAD];

  const int t = threadIdx.x;
  const int lane = t & 63;
  const int wv = t >> 6;
  const int b = blockIdx.x;
  const int gp0 = half * HALF_PIX + b * 8;
  const int n = gp0 >> 10;
  const int l0 = gp0 & 1023;
  const float* sp = sbuf + (size_t)(b * 8 + wv) * P_DIM;

  float4 v[8];
#pragma unroll
  for (int q = 0; q < 8; ++q) v[q] = *(const float4*)(sp + q * 256 + lane * 4);

  if (lane < KPAD - KEEP) kpw[wv][KEEP + lane] = make_int2(0, 0);

  // ---- wave max of |s| -> tight search bounds ----
  float M = 0.f;
#pragma unroll
  for (int q = 0; q < 8; ++q) {
    M = fmaxf(M, fabsf(v[q].x)); M = fmaxf(M, fabsf(v[q].y));
    M = fmaxf(M, fabsf(v[q].z)); M = fmaxf(M, fabsf(v[q].w));
  }
#pragma unroll
  for (int off = 1; off < 64; off <<= 1) M = fmaxf(M, __shfl_xor(M, off));
  const unsigned bitsM = __float_as_uint(M);

  // ---- exact threshold search on positive-float bit pattern.
  //      invariant: count(>=lo) >= KEEP > count(>=hi).
  //      interpolation step (counts ~linear in bits locally) alternated with
  //      bisection for a worst-case bound; exactness from the invariant. ----
  unsigned lo = 0u, hi = bitsM + 1u;
  unsigned cl = 2048u, ch = 0u;
  unsigned m = (bitsM > (1u << 23)) ? (bitsM - (1u << 23)) : ((lo + hi) >> 1);
  int it = 0;
  while (hi - lo > 1u) {
    float mf = __uint_as_float(m);
    unsigned cnt = 0;
#pragma unroll
    for (int q = 0; q < 8; ++q) {
      cnt += (unsigned)__popcll(__ballot(fabsf(v[q].x) >= mf));
      cnt += (unsigned)__popcll(__ballot(fabsf(v[q].y) >= mf));
      cnt += (unsigned)__popcll(__ballot(fabsf(v[q].z) >= mf));
      cnt += (unsigned)__popcll(__ballot(fabsf(v[q].w) >= mf));
    }
    if (cnt >= KEEP) { lo = m; cl = cnt; } else { hi = m; ch = cnt; }
    if (hi - lo <= 1u) break;
    unsigned span = hi - lo;
    unsigned step;
    if ((++it & 1) != 0) {
      float frac = (float)(cl - KEEP) / (float)(cl - ch);   // cl > ch always
      step = (unsigned)(frac * (float)span);
    } else {
      step = span >> 1;
    }
    if (step < 1u) step = 1u;
    if (step > span - 1u) step = span - 1u;
    m = lo + step;
  }
  const float V = __uint_as_float(lo);
  const float Vp = __uint_as_float(lo + 1u);

  unsigned gt = 0;
#pragma unroll
  for (int q = 0; q < 8; ++q) {
    gt += (unsigned)__popcll(__ballot(fabsf(v[q].x) >= Vp));
    gt += (unsigned)__popcll(__ballot(fabsf(v[q].y) >= Vp));
    gt += (unsigned)__popcll(__ballot(fabsf(v[q].z) >= Vp));
    gt += (unsigned)__popcll(__ballot(fabsf(v[q].w) >= Vp));
  }
  const unsigned rrem = (unsigned)KEEP - gt;

  unsigned gmask[8], tmask[8];
#pragma unroll
  for (int q = 0; q < 8; ++q) {
    const float* f = (const float*)&v[q];
    unsigned gm = 0, tm = 0;
#pragma unroll
    for (int rr = 0; rr < 4; ++rr) {
      float av = fabsf(f[rr]);
      if (av >= Vp) gm |= (1u << rr);
      else if (av >= V) tm |= (1u << rr);
    }
    gmask[q] = gm; tmask[q] = tm;
  }

  const unsigned long long lowm = (1ull << lane) - 1ull;
  unsigned base = 0, tiebase = 0;
  float Ssum = 0.f;
#pragma unroll
  for (int q = 0; q < 8; ++q) {
    const float* f = (const float*)&v[q];
    unsigned teq = 0, myeqb = 0;
#pragma unroll
    for (int rr = 0; rr < 4; ++rr) {
      unsigned long long beq = __ballot((tmask[q] >> rr) & 1u);
      teq += (unsigned)__popcll(beq);
      myeqb += (unsigned)__popcll(beq & lowm);
    }
    unsigned km = gmask[q];
    {
      unsigned cum = 0;
#pragma unroll
      for (int rr = 0; rr < 4; ++rr) {
        if ((tmask[q] >> rr) & 1u) {
          if (tiebase + myeqb + cum < rrem) km |= (1u << rr);
          ++cum;
        }
      }
    }
    unsigned long long bk[4];
    unsigned tot = 0, myb = 0;
#pragma unroll
    for (int rr = 0; rr < 4; ++rr) {
      bk[rr] = __ballot((km >> rr) & 1u);
      tot += (unsigned)__popcll(bk[rr]);
      myb += (unsigned)__popcll(bk[rr] & lowm);
    }
    {
      unsigned cum = 0;
#pragma unroll
      for (int rr = 0; rr < 4; ++rr) {
        if ((km >> rr) & 1u) {
          unsigned pos = base + myb + cum;
          kpw[wv][pos] = make_int2(q * 256 + lane * 4 + rr, __float_as_int(f[rr]));
          Ssum += f[rr];
          ++cum;
        }
      }
    }
    base += tot;
    tiebase += teq;
  }

#pragma unroll
  for (int off = 1; off < 64; off <<= 1) Ssum += __shfl_xor(Ssum, off);
  const float invS = 1.0f / Ssum;

  __builtin_amdgcn_wave_barrier();

  // ---- recon: out_c = invS * sum_kept s_p * pool_h[p][c], c = 4*lane+j
  //      fp16 rows (512 B/wave), 4-wide groups, 1-group-ahead prefetch ----
  float a0 = 0.f, a1 = 0.f, a2 = 0.f, a3 = 0.f;
  const u16* pb = pool_h + 4 * lane;
  int2 e[4];
  uint2 r[4];
#pragma unroll
  for (int j = 0; j < 4; ++j) e[j] = kpw[wv][j];
#pragma unroll
  for (int j = 0; j < 4; ++j) r[j] = *(const uint2*)(pb + (size_t)e[j].x * C_DIM);
  for (int k = 0; k < KPAD; k += 4) {
    int kn = (k + 4 < KPAD) ? k + 4 : 0;
    int2 en[4];
    uint2 rn[4];
#pragma unroll
    for (int j = 0; j < 4; ++j) en[j] = kpw[wv][kn + j];
#pragma unroll
    for (int j = 0; j < 4; ++j) rn[j] = *(const uint2*)(pb + (size_t)en[j].x * C_DIM);
#pragma unroll
    for (int j = 0; j < 4; ++j) {
      float w = __int_as_float(e[j].y);
      float f0 = __half2float(__ushort_as_half((u16)(r[j].x & 0xffffu)));
      float f1 = __half2float(__ushort_as_half((u16)(r[j].x >> 16)));
      float f2 = __half2float(__ushort_as_half((u16)(r[j].y & 0xffffu)));
      float f3 = __half2float(__ushort_as_half((u16)(r[j].y >> 16)));
      a0 = fmaf(w, f0, a0); a1 = fmaf(w, f1, a1);
      a2 = fmaf(w, f2, a2); a3 = fmaf(w, f3, a3);
    }
#pragma unroll
    for (int j = 0; j < 4; ++j) { e[j] = en[j]; r[j] = rn[j]; }
  }
  a0 *= invS; a1 *= invS; a2 *= invS; a3 *= invS;

  *(float4*)&tbuf[wv][4 * lane] = make_float4(a0, a1, a2, a3);
  __syncthreads();

  {
    int c = t >> 1, lq = t & 1;
    float4 o = make_float4(tbuf[4 * lq + 0][c], tbuf[4 * lq + 1][c],
                           tbuf[4 * lq + 2][c], tbuf[4 * lq + 3][c]);
    *(float4*)(out + ((size_t)(n * C_DIM + c)) * L_DIM + l0 + 4 * lq) = o;
  }
}

// ---------------- launch ----------------
// d_ws layout (~87 MB):
//   sbuf 67,108,864 | xh/xl 2 x 8,388,608 | ah/al 2 x 1,048,576
//   pool_h 1,048,576 | pinv 8,192
extern "C" void kernel_launch(void* const* d_in, const int* in_sizes, int n_in,
                              void* d_out, int out_size, void* d_ws, size_t ws_size,
                              hipStream_t stream) {
  const float* x = (const float*)d_in[0];
  const float* pool = (const float*)d_in[1];
  float* out = (float*)d_out;
  char* wsb = (char*)d_ws;
  float* sbuf = (float*)wsb;
  u16* xh = (u16*)(wsb + 67108864);
  u16* xl = xh + 4194304;
  u16* ah = xl + 4194304;
  u16* al = ah + 524288;
  u16* ph = al + 524288;
  float* pinv = (float*)(ph + 524288);

  k_pinv<<<P_DIM / 256, 256, 0, stream>>>(pool, pinv);
  k_packpool<<<256, 256, 0, stream>>>(pool, pinv, ah, al, ph);
  k_packx<<<2048, 256, 0, stream>>>(x, xh, xl);
  for (int h = 0; h < 2; ++h) {
    k_mfma<<<1024, 256, 0, stream>>>(ah, al, xh, xl, sbuf, h);
    k_select<<<1024, 512, 0, stream>>>(sbuf, ph, out, h);
  }
}

// Round 2
// 364.471 us; speedup vs baseline: 1.1031x; 1.1031x over previous
//
#include <hip/hip_runtime.h>
#include <hip/hip_fp16.h>

typedef unsigned short u16;
typedef _Float16 half8 __attribute__((ext_vector_type(8)));
typedef float floatx4 __attribute__((ext_vector_type(4)));

#define C_DIM 256
#define P_DIM 2048
#define L_DIM 1024
#define N_DIM 16
#define KEEP 102
#define KPAD 104
#define HALF_PIX 8192   // pixels per half-pass
#define SCALE 256.0f    // 2^8 input pre-scale; both operands scaled -> acc at 2^16.
                        // Downstream is scale-invariant (topk order + w/Sum(w)).

__device__ __forceinline__ void st8(u16* dst, const u16* s) {
  uint4 u;
  u.x = (unsigned)s[0] | ((unsigned)s[1] << 16);
  u.y = (unsigned)s[2] | ((unsigned)s[3] << 16);
  u.z = (unsigned)s[4] | ((unsigned)s[5] << 16);
  u.w = (unsigned)s[6] | ((unsigned)s[7] << 16);
  *(uint4*)dst = u;
}

// fp32 -> fp16 with flush-to-zero of subnormal results (MFMA denormal guard).
// 2^-14 = fp16 min normal; dropped mass is < 2^-30 at true scale.
__device__ __forceinline__ u16 f2h_ftz(float v) {
  if (fabsf(v) < 6.103515625e-5f) return 0;
  return __half_as_ushort(__float2half(v));
}

// ---------------- kernel 1a: pinv[p] = 1/||pool_p|| ----------------
__global__ __launch_bounds__(256) void k_pinv(const float* __restrict__ pool,
                                              float* __restrict__ pinv) {
  int p = blockIdx.x * 256 + threadIdx.x;
  const float4* row = (const float4*)(pool + (size_t)p * C_DIM);
  float s = 0.f;
#pragma unroll
  for (int i = 0; i < C_DIM / 4; ++i) {
    float4 v = row[i];
    s += v.x * v.x + v.y * v.y + v.z * v.z + v.w * v.w;
  }
  pinv[p] = 1.0f / sqrtf(s);
}

// ------- kernel 1b: pack pool*pinv*2^8 into MFMA-A frag order, fp16 hi/lo split,
//         and a raw fp16 copy of pool for the recon gather -------------------
// frag element (pm, ks, lane, j): p = pm*16 + (lane&15), c = ks*32 + (lane>>4)*8 + j
__global__ __launch_bounds__(256) void k_packpool(const float* __restrict__ pool,
                                                  const float* __restrict__ pinv,
                                                  u16* __restrict__ ah,
                                                  u16* __restrict__ al,
                                                  u16* __restrict__ ph) {
  int tid = blockIdx.x * 256 + threadIdx.x;     // 65536 = 128*8*64
  int lane = tid & 63;
  int ks = (tid >> 6) & 7;
  int pm = tid >> 9;
  int p = pm * 16 + (lane & 15);
  int c0 = ks * 32 + ((lane >> 4) << 3);
  float sc = pinv[p] * SCALE;
  const float* src = pool + (size_t)p * C_DIM + c0;
  u16 h8[8], l8[8], p8[8];
#pragma unroll
  for (int j = 0; j < 8; ++j) {
    float raw = src[j];
    p8[j] = __half_as_ushort(__float2half(raw));
    float v = raw * sc;
    u16 h = f2h_ftz(v);
    float r = v - __half2float(__ushort_as_half(h));  // exact (Sterbenz range)
    h8[j] = h;
    l8[j] = f2h_ftz(r);
  }
  size_t o = (size_t)tid * 8;
  st8(ah + o, h8); st8(al + o, l8);
  st8(ph + (size_t)p * C_DIM + c0, p8);
}

// ------- kernel 1c: pack x*2^8 into MFMA-B fragment order, fp16 hi/lo split ----
// frag element (pn, ks, lane, j): pix = pn*16 + (lane&15), c = ks*32 + (lane>>4)*8 + j
__global__ __launch_bounds__(256) void k_packx(const float* __restrict__ x,
                                               u16* __restrict__ xh,
                                               u16* __restrict__ xl) {
  int tid = blockIdx.x * 256 + threadIdx.x;     // 524288 = 1024*8*64
  int lane = tid & 63;
  int ks = (tid >> 6) & 7;
  int pn = tid >> 9;
  int pix = pn * 16 + (lane & 15);
  int n = pix >> 10, l = pix & 1023;
  int c0 = ks * 32 + ((lane >> 4) << 3);
  const float* src = x + ((size_t)(n * C_DIM + c0)) * L_DIM + l;
  u16 h8[8], l8[8];
#pragma unroll
  for (int j = 0; j < 8; ++j) {
    float v = src[(size_t)j * L_DIM] * SCALE;
    u16 h = f2h_ftz(v);
    float r = v - __half2float(__ushort_as_half(h));
    h8[j] = h;
    l8[j] = f2h_ftz(r);
  }
  size_t o = (size_t)tid * 8;
  st8(xh + o, h8); st8(xl + o, l8);
}

// ---------------- kernel A: sbuf[pixLocal][p] via fp16x2 MFMA (3 products) ---
// One half (8192 pixels). grid 1024 = pT(16) x pixT(64); 256 thr / 4 waves.
__global__ __launch_bounds__(256, 3) void k_mfma(const u16* __restrict__ ah_,
                                                 const u16* __restrict__ al_,
                                                 const u16* __restrict__ xh_,
                                                 const u16* __restrict__ xl_,
                                                 float* __restrict__ sbuf,
                                                 int half) {
  const int t = threadIdx.x, lane = t & 63, w = t >> 6;
  const int pT = blockIdx.x & 15, pixT = blockIdx.x >> 4;   // pixT 0..63
  const int pmBase = pT * 8 + w * 2;
  const int pnBase = half * 512 + pixT * 8;
  const half8* A8h = (const half8*)ah_;
  const half8* A8l = (const half8*)al_;
  const half8* B8h = (const half8*)xh_;
  const half8* B8l = (const half8*)xl_;

  floatx4 acc[2][8];
#pragma unroll
  for (int mt = 0; mt < 2; ++mt)
#pragma unroll
    for (int nt = 0; nt < 8; ++nt) acc[mt][nt] = (floatx4){0.f, 0.f, 0.f, 0.f};

#pragma unroll 1
  for (int ks = 0; ks < 8; ++ks) {
    const size_t ao = (size_t)ks * 64 + lane;
    half8 aH[2], aL[2];
#pragma unroll
    for (int mt = 0; mt < 2; ++mt) {
      size_t idx = (size_t)(pmBase + mt) * 512 + ao;
      aH[mt] = A8h[idx]; aL[mt] = A8l[idx];
    }
#pragma unroll
    for (int nt = 0; nt < 8; ++nt) {
      size_t bidx = (size_t)(pnBase + nt) * 512 + ao;
      half8 bh = B8h[bidx], bl = B8l[bidx];
#pragma unroll
      for (int mt = 0; mt < 2; ++mt) {
        floatx4 c = acc[mt][nt];
        c = __builtin_amdgcn_mfma_f32_16x16x32_f16(aH[mt], bh, c, 0, 0, 0);
        c = __builtin_amdgcn_mfma_f32_16x16x32_f16(aH[mt], bl, c, 0, 0, 0);
        c = __builtin_amdgcn_mfma_f32_16x16x32_f16(aL[mt], bh, c, 0, 0, 0);
        acc[mt][nt] = c;
      }
    }
  }

  const int qr = lane >> 4, cl = lane & 15;
  const int pix0 = pixT * 128;
  const int pbase = pT * 128 + w * 32;
#pragma unroll
  for (int mt = 0; mt < 2; ++mt)
#pragma unroll
    for (int nt = 0; nt < 8; ++nt) {
      float* dst = sbuf + (size_t)(pix0 + nt * 16 + cl) * P_DIM + pbase + mt * 16 + qr * 4;
      *(float4*)dst = make_float4(acc[mt][nt][0], acc[mt][nt][1],
                                  acc[mt][nt][2], acc[mt][nt][3]);
    }
}

// ---------------- kernel B: per-pixel top-102 select + renorm + recon ----
// One half. 512 threads = 8 waves; wave wv owns one pixel. 1024 blocks.
// value (q, rr) at lane: p = q*256 + lane*4 + rr
__global__ __launch_bounds__(512) void k_select(const float* __restrict__ sbuf,
                                                const u16* __restrict__ pool_h,
                                                float* __restrict__ out,
                                                int half) {
  __shared__ __align__(16) float tbuf[8][260];
  __shared__ int2 kpw[8][KPAD];

  const int t = threadIdx.x;
  const int lane = t & 63;
  const int wv = t >> 6;
  const int b = blockIdx.x;
  const int gp0 = half * HALF_PIX + b * 8;
  const int n = gp0 >> 10;
  const int l0 = gp0 & 1023;
  const float* sp = sbuf + (size_t)(b * 8 + wv) * P_DIM;

  float4 v[8];
#pragma unroll
  for (int q = 0; q < 8; ++q) v[q] = *(const float4*)(sp + q * 256 + lane * 4);

  if (lane < KPAD - KEEP) kpw[wv][KEEP + lane] = make_int2(0, 0);

  // ---- wave max of |s| -> tight search bounds ----
  float M = 0.f;
#pragma unroll
  for (int q = 0; q < 8; ++q) {
    M = fmaxf(M, fabsf(v[q].x)); M = fmaxf(M, fabsf(v[q].y));
    M = fmaxf(M, fabsf(v[q].z)); M = fmaxf(M, fabsf(v[q].w));
  }
#pragma unroll
  for (int off = 1; off < 64; off <<= 1) M = fmaxf(M, __shfl_xor(M, off));
  const unsigned bitsM = __float_as_uint(M);

  // ---- exact binary search on positive-float bit pattern, early exit.
  //      invariant: count(>=lo) >= KEEP > count(>=hi)  (round-0 verbatim) ----
  unsigned lo = 0u, hi = bitsM + 1u;
  unsigned m = (bitsM > (5u << 23)) ? (bitsM - (5u << 23)) : ((lo + hi) >> 1);
  while (hi - lo > 1u) {
    float mf = __uint_as_float(m);
    unsigned cnt = 0;
#pragma unroll
    for (int q = 0; q < 8; ++q) {
      cnt += (unsigned)__popcll(__ballot(fabsf(v[q].x) >= mf));
      cnt += (unsigned)__popcll(__ballot(fabsf(v[q].y) >= mf));
      cnt += (unsigned)__popcll(__ballot(fabsf(v[q].z) >= mf));
      cnt += (unsigned)__popcll(__ballot(fabsf(v[q].w) >= mf));
    }
    if (cnt >= KEEP) lo = m; else hi = m;
    m = lo + ((hi - lo) >> 1);
  }
  const float V = __uint_as_float(lo);
  const float Vp = __uint_as_float(lo + 1u);

  unsigned gt = 0;
#pragma unroll
  for (int q = 0; q < 8; ++q) {
    gt += (unsigned)__popcll(__ballot(fabsf(v[q].x) >= Vp));
    gt += (unsigned)__popcll(__ballot(fabsf(v[q].y) >= Vp));
    gt += (unsigned)__popcll(__ballot(fabsf(v[q].z) >= Vp));
    gt += (unsigned)__popcll(__ballot(fabsf(v[q].w) >= Vp));
  }
  const unsigned rrem = (unsigned)KEEP - gt;

  unsigned gmask[8], tmask[8];
#pragma unroll
  for (int q = 0; q < 8; ++q) {
    const float* f = (const float*)&v[q];
    unsigned gm = 0, tm = 0;
#pragma unroll
    for (int rr = 0; rr < 4; ++rr) {
      float av = fabsf(f[rr]);
      if (av >= Vp) gm |= (1u << rr);
      else if (av >= V) tm |= (1u << rr);
    }
    gmask[q] = gm; tmask[q] = tm;
  }

  const unsigned long long lowm = (1ull << lane) - 1ull;
  unsigned base = 0, tiebase = 0;
  float Ssum = 0.f;
#pragma unroll
  for (int q = 0; q < 8; ++q) {
    const float* f = (const float*)&v[q];
    unsigned teq = 0, myeqb = 0;
#pragma unroll
    for (int rr = 0; rr < 4; ++rr) {
      unsigned long long beq = __ballot((tmask[q] >> rr) & 1u);
      teq += (unsigned)__popcll(beq);
      myeqb += (unsigned)__popcll(beq & lowm);
    }
    unsigned km = gmask[q];
    {
      unsigned cum = 0;
#pragma unroll
      for (int rr = 0; rr < 4; ++rr) {
        if ((tmask[q] >> rr) & 1u) {
          if (tiebase + myeqb + cum < rrem) km |= (1u << rr);
          ++cum;
        }
      }
    }
    unsigned long long bk[4];
    unsigned tot = 0, myb = 0;
#pragma unroll
    for (int rr = 0; rr < 4; ++rr) {
      bk[rr] = __ballot((km >> rr) & 1u);
      tot += (unsigned)__popcll(bk[rr]);
      myb += (unsigned)__popcll(bk[rr] & lowm);
    }
    {
      unsigned cum = 0;
#pragma unroll
      for (int rr = 0; rr < 4; ++rr) {
        if ((km >> rr) & 1u) {
          unsigned pos = base + myb + cum;
          kpw[wv][pos] = make_int2(q * 256 + lane * 4 + rr, __float_as_int(f[rr]));
          Ssum += f[rr];
          ++cum;
        }
      }
    }
    base += tot;
    tiebase += teq;
  }

#pragma unroll
  for (int off = 1; off < 64; off <<= 1) Ssum += __shfl_xor(Ssum, off);
  const float invS = 1.0f / Ssum;

  __builtin_amdgcn_wave_barrier();

  // ---- recon: out_c = invS * sum_kept s_p * pool_h[p][c], c = 4*lane+j
  //      fp16 rows (512 B/wave), 4-wide groups, 1-group-ahead prefetch ----
  float a0 = 0.f, a1 = 0.f, a2 = 0.f, a3 = 0.f;
  const u16* pb = pool_h + 4 * lane;
  int2 e[4];
  uint2 r[4];
#pragma unroll
  for (int j = 0; j < 4; ++j) e[j] = kpw[wv][j];
#pragma unroll
  for (int j = 0; j < 4; ++j) r[j] = *(const uint2*)(pb + (size_t)e[j].x * C_DIM);
  for (int k = 0; k < KPAD; k += 4) {
    int kn = (k + 4 < KPAD) ? k + 4 : 0;
    int2 en[4];
    uint2 rn[4];
#pragma unroll
    for (int j = 0; j < 4; ++j) en[j] = kpw[wv][kn + j];
#pragma unroll
    for (int j = 0; j < 4; ++j) rn[j] = *(const uint2*)(pb + (size_t)en[j].x * C_DIM);
#pragma unroll
    for (int j = 0; j < 4; ++j) {
      float w = __int_as_float(e[j].y);
      float f0 = __half2float(__ushort_as_half((u16)(r[j].x & 0xffffu)));
      float f1 = __half2float(__ushort_as_half((u16)(r[j].x >> 16)));
      float f2 = __half2float(__ushort_as_half((u16)(r[j].y & 0xffffu)));
      float f3 = __half2float(__ushort_as_half((u16)(r[j].y >> 16)));
      a0 = fmaf(w, f0, a0); a1 = fmaf(w, f1, a1);
      a2 = fmaf(w, f2, a2); a3 = fmaf(w, f3, a3);
    }
#pragma unroll
    for (int j = 0; j < 4; ++j) { e[j] = en[j]; r[j] = rn[j]; }
  }
  a0 *= invS; a1 *= invS; a2 *= invS; a3 *= invS;

  *(float4*)&tbuf[wv][4 * lane] = make_float4(a0, a1, a2, a3);
  __syncthreads();

  {
    int c = t >> 1, lq = t & 1;
    float4 o = make_float4(tbuf[4 * lq + 0][c], tbuf[4 * lq + 1][c],
                           tbuf[4 * lq + 2][c], tbuf[4 * lq + 3][c]);
    *(float4*)(out + ((size_t)(n * C_DIM + c)) * L_DIM + l0 + 4 * lq) = o;
  }
}

// ---------------- launch ----------------
// d_ws layout (~87 MB):
//   sbuf 67,108,864 | xh/xl 2 x 8,388,608 | ah/al 2 x 1,048,576
//   pool_h 1,048,576 | pinv 8,192
extern "C" void kernel_launch(void* const* d_in, const int* in_sizes, int n_in,
                              void* d_out, int out_size, void* d_ws, size_t ws_size,
                              hipStream_t stream) {
  const float* x = (const float*)d_in[0];
  const float* pool = (const float*)d_in[1];
  float* out = (float*)d_out;
  char* wsb = (char*)d_ws;
  float* sbuf = (float*)wsb;
  u16* xh = (u16*)(wsb + 67108864);
  u16* xl = xh + 4194304;
  u16* ah = xl + 4194304;
  u16* al = ah + 524288;
  u16* ph = al + 524288;
  float* pinv = (float*)(ph + 524288);

  k_pinv<<<P_DIM / 256, 256, 0, stream>>>(pool, pinv);
  k_packpool<<<256, 256, 0, stream>>>(pool, pinv, ah, al, ph);
  k_packx<<<2048, 256, 0, stream>>>(x, xh, xl);
  for (int h = 0; h < 2; ++h) {
    k_mfma<<<1024, 256, 0, stream>>>(ah, al, xh, xl, sbuf, h);
    k_select<<<1024, 512, 0, stream>>>(sbuf, ph, out, h);
  }
}

// Round 3
// 269.838 us; speedup vs baseline: 1.4900x; 1.3507x over previous
//
#include <hip/hip_runtime.h>
#include <hip/hip_fp16.h>

typedef unsigned short u16;
typedef _Float16 half8 __attribute__((ext_vector_type(8)));
typedef float floatx4 __attribute__((ext_vector_type(4)));

#define C_DIM 256
#define P_DIM 2048
#define L_DIM 1024
#define N_DIM 16
#define KEEP 102
#define KPAD 104
#define HALF_PIX 8192   // pixels per half-pass
#define SCALE 256.0f    // 2^8 input pre-scale; both operands scaled -> acc at 2^16.
                        // Downstream is scale-invariant (topk order + w/Sum(w)).

__device__ __forceinline__ void st8(u16* dst, const u16* s) {
  uint4 u;
  u.x = (unsigned)s[0] | ((unsigned)s[1] << 16);
  u.y = (unsigned)s[2] | ((unsigned)s[3] << 16);
  u.z = (unsigned)s[4] | ((unsigned)s[5] << 16);
  u.w = (unsigned)s[6] | ((unsigned)s[7] << 16);
  *(uint4*)dst = u;
}

// fp32 -> fp16 with flush-to-zero of subnormal results (MFMA denormal guard).
__device__ __forceinline__ u16 f2h_ftz(float v) {
  if (fabsf(v) < 6.103515625e-5f) return 0;
  return __half_as_ushort(__float2half(v));
}

// async global->LDS, 16B per lane. LDS dest is wave-uniform base + lane*16.
__device__ __forceinline__ void gl_lds16(const u16* g, u16* l) {
  __builtin_amdgcn_global_load_lds(
      (const __attribute__((address_space(1))) unsigned int*)g,
      (__attribute__((address_space(3))) unsigned int*)l, 16, 0, 0);
}

// ---------------- kernel 1a: pinv[p] = 1/||pool_p|| ----------------
__global__ __launch_bounds__(256) void k_pinv(const float* __restrict__ pool,
                                              float* __restrict__ pinv) {
  int p = blockIdx.x * 256 + threadIdx.x;
  const float4* row = (const float4*)(pool + (size_t)p * C_DIM);
  float s = 0.f;
#pragma unroll
  for (int i = 0; i < C_DIM / 4; ++i) {
    float4 v = row[i];
    s += v.x * v.x + v.y * v.y + v.z * v.z + v.w * v.w;
  }
  pinv[p] = 1.0f / sqrtf(s);
}

// ------- kernel 1b: pack pool*pinv*2^8 into MFMA-A frag order, fp16 hi/lo split,
//         and a raw fp16 copy of pool for the recon gather -------------------
// frag element (pm, ks, lane, j): p = pm*16 + (lane&15), c = ks*32 + (lane>>4)*8 + j
__global__ __launch_bounds__(256) void k_packpool(const float* __restrict__ pool,
                                                  const float* __restrict__ pinv,
                                                  u16* __restrict__ ah,
                                                  u16* __restrict__ al,
                                                  u16* __restrict__ ph) {
  int tid = blockIdx.x * 256 + threadIdx.x;     // 65536 = 128*8*64
  int lane = tid & 63;
  int ks = (tid >> 6) & 7;
  int pm = tid >> 9;
  int p = pm * 16 + (lane & 15);
  int c0 = ks * 32 + ((lane >> 4) << 3);
  float sc = pinv[p] * SCALE;
  const float* src = pool + (size_t)p * C_DIM + c0;
  u16 h8[8], l8[8], p8[8];
#pragma unroll
  for (int j = 0; j < 8; ++j) {
    float raw = src[j];
    p8[j] = __half_as_ushort(__float2half(raw));
    float v = raw * sc;
    u16 h = f2h_ftz(v);
    float r = v - __half2float(__ushort_as_half(h));  // exact (Sterbenz range)
    h8[j] = h;
    l8[j] = f2h_ftz(r);
  }
  size_t o = (size_t)tid * 8;
  st8(ah + o, h8); st8(al + o, l8);
  st8(ph + (size_t)p * C_DIM + c0, p8);
}

// ------- kernel 1c: pack x*2^8 into MFMA-B fragment order, fp16 hi/lo split ----
// frag element (pn, ks, lane, j): pix = pn*16 + (lane&15), c = ks*32 + (lane>>4)*8 + j
__global__ __launch_bounds__(256) void k_packx(const float* __restrict__ x,
                                               u16* __restrict__ xh,
                                               u16* __restrict__ xl) {
  int tid = blockIdx.x * 256 + threadIdx.x;     // 524288 = 1024*8*64
  int lane = tid & 63;
  int ks = (tid >> 6) & 7;
  int pn = tid >> 9;
  int pix = pn * 16 + (lane & 15);
  int n = pix >> 10, l = pix & 1023;
  int c0 = ks * 32 + ((lane >> 4) << 3);
  const float* src = x + ((size_t)(n * C_DIM + c0)) * L_DIM + l;
  u16 h8[8], l8[8];
#pragma unroll
  for (int j = 0; j < 8; ++j) {
    float v = src[(size_t)j * L_DIM] * SCALE;
    u16 h = f2h_ftz(v);
    float r = v - __half2float(__ushort_as_half(h));
    h8[j] = h;
    l8[j] = f2h_ftz(r);
  }
  size_t o = (size_t)tid * 8;
  st8(xh + o, h8); st8(xl + o, l8);
}

// ---------------- kernel A: sbuf[pixLocal][p] via fp16x2 MFMA (3 products) ---
// One half (8192 pixels). grid 1024 = pT(16) x pixT(64); 256 thr / 4 waves.
// B fragments staged to LDS via global_load_lds (shared by all 4 waves),
// double-buffered 2-phase pipeline: stage(ks+1) || compute(ks); one barrier/iter.
__global__ __launch_bounds__(256, 4) void k_mfma(const u16* __restrict__ ah_,
                                                 const u16* __restrict__ al_,
                                                 const u16* __restrict__ xh_,
                                                 const u16* __restrict__ xl_,
                                                 float* __restrict__ sbuf,
                                                 int half) {
  // sB[buf][h/l][nt][lane*8] : 16 KB per buffer, 32 KB total.
  __shared__ u16 sB[2][2][8][512];

  const int t = threadIdx.x, lane = t & 63, w = t >> 6;
  const int pT = blockIdx.x & 15, pixT = blockIdx.x >> 4;   // pixT 0..63
  const int pmBase = pT * 8 + w * 2;
  const int pnBase = half * 512 + pixT * 8;
  const half8* A8h = (const half8*)ah_;
  const half8* A8l = (const half8*)al_;

  // stage assignment: id = w*4+q; arr = id>>3 (0=h,1=l), nt = id&7
  const u16* xsrc[2] = {xh_, xl_};

  floatx4 acc[2][8];
#pragma unroll
  for (int mt = 0; mt < 2; ++mt)
#pragma unroll
    for (int nt = 0; nt < 8; ++nt) acc[mt][nt] = (floatx4){0.f, 0.f, 0.f, 0.f};

  // ---- prologue: stage slab ks=0 into buffer 0 ----
#pragma unroll
  for (int q = 0; q < 4; ++q) {
    int id = w * 4 + q;
    int arr = id >> 3, nt = id & 7;
    const u16* g = xsrc[arr] + ((size_t)(pnBase + nt) * 512 + lane) * 8;
    gl_lds16(g, &sB[0][arr][nt][0]);
  }
  __syncthreads();

#pragma unroll 1
  for (int ks = 0; ks < 8; ++ks) {
    const int cur = ks & 1;
    // A fragments for current ks (direct global -> regs; L2-hot)
    half8 aH[2], aL[2];
    const size_t ao = (size_t)ks * 64 + lane;
#pragma unroll
    for (int mt = 0; mt < 2; ++mt) {
      size_t idx = (size_t)(pmBase + mt) * 512 + ao;
      aH[mt] = A8h[idx]; aL[mt] = A8l[idx];
    }
    // stage next slab into the other buffer
    if (ks < 7) {
#pragma unroll
      for (int q = 0; q < 4; ++q) {
        int id = w * 4 + q;
        int arr = id >> 3, nt = id & 7;
        const u16* g = xsrc[arr] + ((size_t)(pnBase + nt) * 512 + (ks + 1) * 64 + lane) * 8;
        gl_lds16(g, &sB[cur ^ 1][arr][nt][0]);
      }
    }
    // compute from current buffer
#pragma unroll
    for (int nt = 0; nt < 8; ++nt) {
      half8 bh = *(const half8*)&sB[cur][0][nt][lane * 8];
      half8 bl = *(const half8*)&sB[cur][1][nt][lane * 8];
#pragma unroll
      for (int mt = 0; mt < 2; ++mt) {
        floatx4 c = acc[mt][nt];
        c = __builtin_amdgcn_mfma_f32_16x16x32_f16(aH[mt], bh, c, 0, 0, 0);
        c = __builtin_amdgcn_mfma_f32_16x16x32_f16(aH[mt], bl, c, 0, 0, 0);
        c = __builtin_amdgcn_mfma_f32_16x16x32_f16(aL[mt], bh, c, 0, 0, 0);
        acc[mt][nt] = c;
      }
    }
    __syncthreads();   // drains staged loads (vmcnt 0) + protects buffer reuse
  }

  const int qr = lane >> 4, cl = lane & 15;
  const int pix0 = pixT * 128;
  const int pbase = pT * 128 + w * 32;
#pragma unroll
  for (int mt = 0; mt < 2; ++mt)
#pragma unroll
    for (int nt = 0; nt < 8; ++nt) {
      float* dst = sbuf + (size_t)(pix0 + nt * 16 + cl) * P_DIM + pbase + mt * 16 + qr * 4;
      *(float4*)dst = make_float4(acc[mt][nt][0], acc[mt][nt][1],
                                  acc[mt][nt][2], acc[mt][nt][3]);
    }
}

// ---------------- kernel B: per-pixel top-102 select + renorm + recon ----
// One half. 512 threads = 8 waves; wave wv owns one pixel. 1024 blocks.
// value (q, rr) at lane: p = q*256 + lane*4 + rr
__global__ __launch_bounds__(512) void k_select(const float* __restrict__ sbuf,
                                                const u16* __restrict__ pool_h,
                                                float* __restrict__ out,
                                                int half) {
  __shared__ __align__(16) float tbuf[8][260];
  __shared__ int2 kpw[8][KPAD];

  const int t = threadIdx.x;
  const int lane = t & 63;
  const int wv = t >> 6;
  const int b = blockIdx.x;
  const int gp0 = half * HALF_PIX + b * 8;
  const int n = gp0 >> 10;
  const int l0 = gp0 & 1023;
  const float* sp = sbuf + (size_t)(b * 8 + wv) * P_DIM;

  float4 v[8];
#pragma unroll
  for (int q = 0; q < 8; ++q) v[q] = *(const float4*)(sp + q * 256 + lane * 4);

  if (lane < KPAD - KEEP) kpw[wv][KEEP + lane] = make_int2(0, 0);

  // ---- wave max of |s| -> tight search bounds ----
  float M = 0.f;
#pragma unroll
  for (int q = 0; q < 8; ++q) {
    M = fmaxf(M, fabsf(v[q].x)); M = fmaxf(M, fabsf(v[q].y));
    M = fmaxf(M, fabsf(v[q].z)); M = fmaxf(M, fabsf(v[q].w));
  }
#pragma unroll
  for (int off = 1; off < 64; off <<= 1) M = fmaxf(M, __shfl_xor(M, off));
  const unsigned bitsM = __float_as_uint(M);

  // ---- exact binary search on positive-float bit pattern, early exit.
  //      invariant: count(>=lo) >= KEEP > count(>=hi) ----
  unsigned lo = 0u, hi = bitsM + 1u;
  unsigned m = (bitsM > (5u << 23)) ? (bitsM - (5u << 23)) : ((lo + hi) >> 1);
  while (hi - lo > 1u) {
    float mf = __uint_as_float(m);
    unsigned cnt = 0;
#pragma unroll
    for (int q = 0; q < 8; ++q) {
      cnt += (unsigned)__popcll(__ballot(fabsf(v[q].x) >= mf));
      cnt += (unsigned)__popcll(__ballot(fabsf(v[q].y) >= mf));
      cnt += (unsigned)__popcll(__ballot(fabsf(v[q].z) >= mf));
      cnt += (unsigned)__popcll(__ballot(fabsf(v[q].w) >= mf));
    }
    if (cnt >= KEEP) lo = m; else hi = m;
    m = lo + ((hi - lo) >> 1);
  }
  const float V = __uint_as_float(lo);
  const float Vp = __uint_as_float(lo + 1u);

  unsigned gt = 0;
#pragma unroll
  for (int q = 0; q < 8; ++q) {
    gt += (unsigned)__popcll(__ballot(fabsf(v[q].x) >= Vp));
    gt += (unsigned)__popcll(__ballot(fabsf(v[q].y) >= Vp));
    gt += (unsigned)__popcll(__ballot(fabsf(v[q].z) >= Vp));
    gt += (unsigned)__popcll(__ballot(fabsf(v[q].w) >= Vp));
  }
  const unsigned rrem = (unsigned)KEEP - gt;

  unsigned gmask[8], tmask[8];
#pragma unroll
  for (int q = 0; q < 8; ++q) {
    const float* f = (const float*)&v[q];
    unsigned gm = 0, tm = 0;
#pragma unroll
    for (int rr = 0; rr < 4; ++rr) {
      float av = fabsf(f[rr]);
      if (av >= Vp) gm |= (1u << rr);
      else if (av >= V) tm |= (1u << rr);
    }
    gmask[q] = gm; tmask[q] = tm;
  }

  const unsigned long long lowm = (1ull << lane) - 1ull;
  unsigned base = 0, tiebase = 0;
  float Ssum = 0.f;
#pragma unroll
  for (int q = 0; q < 8; ++q) {
    const float* f = (const float*)&v[q];
    unsigned teq = 0, myeqb = 0;
#pragma unroll
    for (int rr = 0; rr < 4; ++rr) {
      unsigned long long beq = __ballot((tmask[q] >> rr) & 1u);
      teq += (unsigned)__popcll(beq);
      myeqb += (unsigned)__popcll(beq & lowm);
    }
    unsigned km = gmask[q];
    {
      unsigned cum = 0;
#pragma unroll
      for (int rr = 0; rr < 4; ++rr) {
        if ((tmask[q] >> rr) & 1u) {
          if (tiebase + myeqb + cum < rrem) km |= (1u << rr);
          ++cum;
        }
      }
    }
    unsigned long long bk[4];
    unsigned tot = 0, myb = 0;
#pragma unroll
    for (int rr = 0; rr < 4; ++rr) {
      bk[rr] = __ballot((km >> rr) & 1u);
      tot += (unsigned)__popcll(bk[rr]);
      myb += (unsigned)__popcll(bk[rr] & lowm);
    }
    {
      unsigned cum = 0;
#pragma unroll
      for (int rr = 0; rr < 4; ++rr) {
        if ((km >> rr) & 1u) {
          unsigned pos = base + myb + cum;
          kpw[wv][pos] = make_int2(q * 256 + lane * 4 + rr, __float_as_int(f[rr]));
          Ssum += f[rr];
          ++cum;
        }
      }
    }
    base += tot;
    tiebase += teq;
  }

#pragma unroll
  for (int off = 1; off < 64; off <<= 1) Ssum += __shfl_xor(Ssum, off);
  const float invS = 1.0f / Ssum;

  __builtin_amdgcn_wave_barrier();

  // ---- recon: out_c = invS * sum_kept s_p * pool_h[p][c], c = 4*lane+j
  //      fp16 rows (512 B/wave), 4-wide groups, 1-group-ahead prefetch ----
  float a0 = 0.f, a1 = 0.f, a2 = 0.f, a3 = 0.f;
  const u16* pb = pool_h + 4 * lane;
  int2 e[4];
  uint2 r[4];
#pragma unroll
  for (int j = 0; j < 4; ++j) e[j] = kpw[wv][j];
#pragma unroll
  for (int j = 0; j < 4; ++j) r[j] = *(const uint2*)(pb + (size_t)e[j].x * C_DIM);
  for (int k = 0; k < KPAD; k += 4) {
    int kn = (k + 4 < KPAD) ? k + 4 : 0;
    int2 en[4];
    uint2 rn[4];
#pragma unroll
    for (int j = 0; j < 4; ++j) en[j] = kpw[wv][kn + j];
#pragma unroll
    for (int j = 0; j < 4; ++j) rn[j] = *(const uint2*)(pb + (size_t)en[j].x * C_DIM);
#pragma unroll
    for (int j = 0; j < 4; ++j) {
      float w = __int_as_float(e[j].y);
      float f0 = __half2float(__ushort_as_half((u16)(r[j].x & 0xffffu)));
      float f1 = __half2float(__ushort_as_half((u16)(r[j].x >> 16)));
      float f2 = __half2float(__ushort_as_half((u16)(r[j].y & 0xffffu)));
      float f3 = __half2float(__ushort_as_half((u16)(r[j].y >> 16)));
      a0 = fmaf(w, f0, a0); a1 = fmaf(w, f1, a1);
      a2 = fmaf(w, f2, a2); a3 = fmaf(w, f3, a3);
    }
#pragma unroll
    for (int j = 0; j < 4; ++j) { e[j] = en[j]; r[j] = rn[j]; }
  }
  a0 *= invS; a1 *= invS; a2 *= invS; a3 *= invS;

  *(float4*)&tbuf[wv][4 * lane] = make_float4(a0, a1, a2, a3);
  __syncthreads();

  {
    int c = t >> 1, lq = t & 1;
    float4 o = make_float4(tbuf[4 * lq + 0][c], tbuf[4 * lq + 1][c],
                           tbuf[4 * lq + 2][c], tbuf[4 * lq + 3][c]);
    *(float4*)(out + ((size_t)(n * C_DIM + c)) * L_DIM + l0 + 4 * lq) = o;
  }
}

// ---------------- launch ----------------
// d_ws layout (~87 MB):
//   sbuf 67,108,864 | xh/xl 2 x 8,388,608 | ah/al 2 x 1,048,576
//   pool_h 1,048,576 | pinv 8,192
extern "C" void kernel_launch(void* const* d_in, const int* in_sizes, int n_in,
                              void* d_out, int out_size, void* d_ws, size_t ws_size,
                              hipStream_t stream) {
  const float* x = (const float*)d_in[0];
  const float* pool = (const float*)d_in[1];
  float* out = (float*)d_out;
  char* wsb = (char*)d_ws;
  float* sbuf = (float*)wsb;
  u16* xh = (u16*)(wsb + 67108864);
  u16* xl = xh + 4194304;
  u16* ah = xl + 4194304;
  u16* al = ah + 524288;
  u16* ph = al + 524288;
  float* pinv = (float*)(ph + 524288);

  k_pinv<<<P_DIM / 256, 256, 0, stream>>>(pool, pinv);
  k_packpool<<<256, 256, 0, stream>>>(pool, pinv, ah, al, ph);
  k_packx<<<2048, 256, 0, stream>>>(x, xh, xl);
  for (int h = 0; h < 2; ++h) {
    k_mfma<<<1024, 256, 0, stream>>>(ah, al, xh, xl, sbuf, h);
    k_select<<<1024, 512, 0, stream>>>(sbuf, ph, out, h);
  }
}